// Round 9
// baseline (203.472 us; speedup 1.0000x reference)
//
#include <hip/hip_runtime.h>
#include <hip/hip_bf16.h>

// Hmoe: gate = sigmoid(x @ w + b); tree-product over 6 levels -> P (32768 x 64);
// out = P @ responses.
// prep: w -> wFs bf16 hi/lo in MFMA B-fragment order (512 KB, chunk-contiguous);
//       responses -> RT bf16 [2048][64] (row-major, for out_kernel).
// gate v9: block = 64 rows, 4 waves, 256 thr; grid 512 = exactly 2 blocks/CU.
//   K processed in 8 chunks of 256; each chunk's w (64 KB: 64 nodes x 256 k x
//   hi/lo) staged ONCE into LDS -> only 2 barriers per chunk (~1000 cyc of
//   compute between drains, covering HBM latency). x loaded to regs one full
//   chunk ahead (16 float4/wave in flight); A-frags built with __shfl
//   (wave-local, no LDS tile). w for chunk c+1 reg-prefetched during chunk c.
//   Epilogue: reuse w-LDS as gate buffer; sigmoid + tree -> P bf16.
// out_kernel: unchanged R4 structure (128x128 tile, LDS-staged, ~45 us).

typedef short bf16x8 __attribute__((ext_vector_type(8)));
typedef float f32x4  __attribute__((ext_vector_type(4)));

#define BS    32768
#define DIMX  2048
#define NODES 63
#define NL    64
#define DIMY  2048

__device__ __forceinline__ unsigned short f2bf(float f) {
    union { float f; unsigned int u; } v; v.f = f;
    unsigned int r = v.u + 0x7FFFu + ((v.u >> 16) & 1u);   // RNE
    return (unsigned short)(r >> 16);
}
__device__ __forceinline__ float bf2f(unsigned short h) {
    union { float f; unsigned int u; } v; v.u = ((unsigned int)h) << 16;
    return v.f;
}

// ---------------- kernel 0: prep --------------------------------------------
// wFs: frag id = ((k64*2 + kk)*4 + g16)*2 + hl ; element (lane l, e 0..7) =
//   wT[node = g16*16 + (l&15)][kcol = k64*64 + kk*32 + (l>>4)*8 + e], hi/lo.
//   256-k chunk c = frag ids [c*64, c*64+64) = contiguous 64 KB.
// RT: plain [n][k] = [2048][64] bf16 row-major.
__global__ __launch_bounds__(256) void prep(const float* __restrict__ w,
                                            const float* __restrict__ R,
                                            unsigned short* __restrict__ wFs,
                                            unsigned short* __restrict__ RT) {
    int f = blockIdx.x * 256 + threadIdx.x;     // 0..393215
    if (f < 262144) {                           // wFs
        int e   = f & 7;
        int l   = (f >> 3) & 63;
        int hl  = (f >> 9) & 1;
        int g16 = (f >> 10) & 3;
        int kk  = (f >> 12) & 1;
        int k   = f >> 13;                      // 0..31
        int n    = g16 * 16 + (l & 15);
        int kcol = k * 64 + kk * 32 + (l >> 4) * 8 + e;
        float v = (n < NODES) ? w[(size_t)kcol * NODES + n] : 0.0f;
        unsigned short h = f2bf(v);
        wFs[f] = hl ? f2bf(v - bf2f(h)) : h;
    } else {                                    // RT
        int f2 = f - 262144;                    // 0..131071
        int n = f2 >> 6;
        int k = f2 & 63;
        RT[f2] = f2bf(R[(size_t)k * DIMY + n]);
    }
}

// ---------------- kernel 1: gate GEMM + tree -> P ----------------------------
#define GBM    64                   // rows per block (4 waves x 16)
#define CHUNK  256                  // k per LDS-resident w chunk
#define NCHUNK (DIMX / CHUNK)       // 8
#define JSTEPS (CHUNK / 32)         // 8

__global__ __launch_bounds__(256, 2) void gate_kernel(const float* __restrict__ x,
                                                      const unsigned short* __restrict__ wFs,
                                                      const float* __restrict__ bias,
                                                      unsigned short* __restrict__ P) {
    __shared__ __align__(16) unsigned char smem[65536];     // w chunk / gate buf
    unsigned short* wl = (unsigned short*)smem;
    float (*gl)[NL + 1] = (float (*)[NL + 1])smem;          // 64 x 65 f32 (16.6 KB)

    const int t    = threadIdx.x;
    const int lane = t & 63;
    const int wv   = t >> 6;        // 4 waves x 16 rows
    const int lr   = lane & 15;
    const int lg   = lane >> 4;
    const int m0   = blockIdx.x * GBM;

    // x: lane (r = lane>>2, c = lane&3) covers 16 rows x 32 k per step
    const int xr = lane >> 2;
    const int xc = lane & 3;
    const float* xw = x + (size_t)(m0 + wv * 16 + xr) * DIMX + xc * 8;
    const int srcl = (lr << 2) | lg;            // shfl src for A-frag

    const uint4* wsrc = (const uint4*)wFs;      // chunk c: idx c*4096 + i*256 + t
    uint4* wdst = (uint4*)smem;

    f32x4 acc[4];
    #pragma unroll
    for (int g = 0; g < 4; ++g) acc[g] = (f32x4){0.f, 0.f, 0.f, 0.f};

    // prefetch chunk 0 (w and x)
    uint4  wreg[16];
    float4 xreg[16];
    #pragma unroll
    for (int i = 0; i < 16; ++i) wreg[i] = wsrc[i * 256 + t];
    #pragma unroll
    for (int j = 0; j < JSTEPS; ++j) {
        xreg[2 * j]     = *(const float4*)(xw + j * 32);
        xreg[2 * j + 1] = *(const float4*)(xw + j * 32 + 4);
    }

    for (int c = 0; c < NCHUNK; ++c) {
        if (c) __syncthreads();                 // prev chunk's LDS reads done
        #pragma unroll
        for (int i = 0; i < 16; ++i) wdst[i * 256 + t] = wreg[i];
        __syncthreads();                        // w chunk visible
        if (c + 1 < NCHUNK) {                   // reg-prefetch next w chunk;
            #pragma unroll                      // consumed after next barrier
            for (int i = 0; i < 16; ++i)
                wreg[i] = wsrc[(c + 1) * 4096 + i * 256 + t];
        }
        #pragma unroll
        for (int j = 0; j < JSTEPS; ++j) {
            float4 v0 = xreg[2 * j], v1 = xreg[2 * j + 1];
            int q0, q1, q2, q3;
            {
                union { __hip_bfloat162 h; int i; } u;
                u.h = __float22bfloat162_rn(make_float2(v0.x, v0.y)); q0 = u.i;
                u.h = __float22bfloat162_rn(make_float2(v0.z, v0.w)); q1 = u.i;
                u.h = __float22bfloat162_rn(make_float2(v1.x, v1.y)); q2 = u.i;
                u.h = __float22bfloat162_rn(make_float2(v1.z, v1.w)); q3 = u.i;
            }
            if (c + 1 < NCHUNK) {               // reload this slot for chunk c+1
                xreg[2 * j]     = *(const float4*)(xw + (c + 1) * CHUNK + j * 32);
                xreg[2 * j + 1] = *(const float4*)(xw + (c + 1) * CHUNK + j * 32 + 4);
            }
            union { int i[4]; bf16x8 v; } A;
            A.i[0] = __shfl(q0, srcl);
            A.i[1] = __shfl(q1, srcl);
            A.i[2] = __shfl(q2, srcl);
            A.i[3] = __shfl(q3, srcl);
            #pragma unroll
            for (int g = 0; g < 4; ++g) {
                const unsigned short* fb = wl + (size_t)((j * 4 + g) * 2) * 512 + lane * 8;
                bf16x8 bh = *(const bf16x8*)fb;
                bf16x8 bo = *(const bf16x8*)(fb + 512);
                acc[g] = __builtin_amdgcn_mfma_f32_16x16x32_bf16(A.v, bh, acc[g], 0, 0, 0);
                acc[g] = __builtin_amdgcn_mfma_f32_16x16x32_bf16(A.v, bo, acc[g], 0, 0, 0);
            }
        }
    }

    // ---- epilogue: reuse smem as gate buffer ----
    __syncthreads();                  // all w reads done
    #pragma unroll
    for (int g = 0; g < 4; ++g) {
        const int col = g * 16 + lr;
        const float bb = (col < NODES) ? bias[col] : 0.0f;
        #pragma unroll
        for (int i = 0; i < 4; ++i) {
            float s = acc[g][i] + bb;           // D-frag: row = lg*4+i, col
            gl[wv * 16 + lg * 4 + i][col] = 1.0f / (1.0f + __expf(-s));
        }
    }
    __syncthreads();                  // gl visible

    // tree: 4 threads/row (verified R2 structure); leaf L = m + 16*b4 + 32*b5
    {
        const int rr = t >> 2;        // 0..63
        const int b4 = t & 1, b5 = (t >> 1) & 1;
        const float* g = gl[rr];
        float a2[2], a4[4], a8[8], a16[16];
        float g0 = g[0];
        a2[0] = g0; a2[1] = 1.f - g0;
        #pragma unroll
        for (int m = 0; m < 4; ++m) {
            float gg = g[1 + (m & 1)];
            a4[m] = a2[m & 1] * ((m & 2) ? (1.f - gg) : gg);
        }
        #pragma unroll
        for (int m = 0; m < 8; ++m) {
            float gg = g[3 + (m & 3)];
            a8[m] = a4[m & 3] * ((m & 4) ? (1.f - gg) : gg);
        }
        #pragma unroll
        for (int m = 0; m < 16; ++m) {
            float gg = g[7 + (m & 7)];
            a16[m] = a8[m & 7] * ((m & 8) ? (1.f - gg) : gg);
        }
        unsigned short o[16];
        #pragma unroll
        for (int m = 0; m < 16; ++m) {
            float p = a16[m];
            float g5 = g[15 + m];                 // level 5: node 15 + (L&15)
            p *= b4 ? (1.f - g5) : g5;
            float g6 = g[31 + m + 16 * b4];       // level 6: node 31 + (L&31)
            p *= b5 ? (1.f - g6) : g6;
            o[m] = f2bf(p);
        }
        uint4 q0, q1;
        q0.x = (unsigned)o[0]  | ((unsigned)o[1]  << 16);
        q0.y = (unsigned)o[2]  | ((unsigned)o[3]  << 16);
        q0.z = (unsigned)o[4]  | ((unsigned)o[5]  << 16);
        q0.w = (unsigned)o[6]  | ((unsigned)o[7]  << 16);
        q1.x = (unsigned)o[8]  | ((unsigned)o[9]  << 16);
        q1.y = (unsigned)o[10] | ((unsigned)o[11] << 16);
        q1.z = (unsigned)o[12] | ((unsigned)o[13] << 16);
        q1.w = (unsigned)o[14] | ((unsigned)o[15] << 16);
        uint4* dst = (uint4*)&P[(size_t)(m0 + rr) * NL + 16 * b4 + 32 * b5];
        dst[0] = q0;
        dst[1] = q1;
    }
}

// ---------------- kernel 2: out = P @ RT^T (P: MxK=64, RT: [n][k]) -----------
#define OBM  128
#define OBN  128
#define OLD  72

__global__ __launch_bounds__(256) void out_kernel(const unsigned short* __restrict__ P,
                                                  const unsigned short* __restrict__ RT,
                                                  float* __restrict__ out) {
    __shared__ __align__(16) unsigned short ps[OBM][OLD];
    __shared__ __align__(16) unsigned short rs[OBN][OLD];
    const int t  = threadIdx.x;
    const int n0 = blockIdx.x * OBN;
    const int m0 = blockIdx.y * OBM;

    #pragma unroll
    for (int p = 0; p < 4; ++p) {
        int c   = p * 256 + t;
        int row = c >> 3;
        int c8  = c & 7;
        *(uint4*)&ps[row][c8 * 8] = *(const uint4*)&P [(size_t)(m0 + row) * NL + c8 * 8];
        *(uint4*)&rs[row][c8 * 8] = *(const uint4*)&RT[(size_t)(n0 + row) * NL + c8 * 8];
    }
    __syncthreads();

    const int lane = t & 63;
    const int wv   = t >> 6;
    const int wm   = (wv >> 1) * 64;   // wave tile 64x64
    const int wn   = (wv & 1) * 64;
    const int lr   = lane & 15;
    const int lg   = lane >> 4;

    f32x4 acc[4][4];
    #pragma unroll
    for (int rf = 0; rf < 4; ++rf)
        #pragma unroll
        for (int cf = 0; cf < 4; ++cf) acc[rf][cf] = (f32x4){0.f, 0.f, 0.f, 0.f};

    #pragma unroll
    for (int kk = 0; kk < NL; kk += 32) {
        bf16x8 a[4], bb[4];
        #pragma unroll
        for (int rf = 0; rf < 4; ++rf)
            a[rf] = *(const bf16x8*)&ps[wm + rf * 16 + lr][kk + lg * 8];
        #pragma unroll
        for (int cf = 0; cf < 4; ++cf)
            bb[cf] = *(const bf16x8*)&rs[wn + cf * 16 + lr][kk + lg * 8];
        #pragma unroll
        for (int rf = 0; rf < 4; ++rf)
            #pragma unroll
            for (int cf = 0; cf < 4; ++cf)
                acc[rf][cf] = __builtin_amdgcn_mfma_f32_16x16x32_bf16(a[rf], bb[cf],
                                                                      acc[rf][cf], 0, 0, 0);
    }

    #pragma unroll
    for (int rf = 0; rf < 4; ++rf) {
        #pragma unroll
        for (int cf = 0; cf < 4; ++cf) {
            #pragma unroll
            for (int i = 0; i < 4; ++i) {
                int row = m0 + wm + rf * 16 + lg * 4 + i;
                int col = n0 + wn + cf * 16 + lr;
                out[(size_t)row * DIMY + col] = acc[rf][cf][i];
            }
        }
    }
}

extern "C" void kernel_launch(void* const* d_in, const int* in_sizes, int n_in,
                              void* d_out, int out_size, void* d_ws, size_t ws_size,
                              hipStream_t stream) {
    const float* x = (const float*)d_in[0];
    const float* w = (const float*)d_in[1];
    const float* b = (const float*)d_in[2];
    const float* R = (const float*)d_in[3];
    float* out = (float*)d_out;

    char* ws = (char*)d_ws;
    unsigned short* wFs = (unsigned short*)ws;                  // 512 KB
    unsigned short* RT  = (unsigned short*)(ws + 524288);       // 256 KB
    unsigned short* P   = (unsigned short*)(ws + 786432);       // 4 MB

    prep<<<dim3(1536), 256, 0, stream>>>(w, R, wFs, RT);
    gate_kernel<<<dim3(BS / GBM), 256, 0, stream>>>(x, wFs, b, P);
    out_kernel<<<dim3(DIMY / OBN, BS / OBM), 256, 0, stream>>>(P, RT, out);
}

// Round 10
// 183.648 us; speedup vs baseline: 1.1079x; 1.1079x over previous
//
#include <hip/hip_runtime.h>
#include <hip/hip_bf16.h>

// Hmoe: gate = sigmoid(x @ w + b); tree-product over 6 levels -> P (32768 x 64);
// out = P @ responses.
// prep: w -> wFs bf16 hi/lo in MFMA B-fragment order (512 KB);
//       responses -> RTs bf16 in B-fragment order (256 KB).
// fused v10 — slab-linear x, LDS-panel K-loop, fully fused:
//   phase 0: block = 16 rows; read the 128 KB x-slab LINEARLY (fillBuffer-like
//            stream), cvt to bf16, store to a 64 KB XOR-swizzled LDS panel.
//   phase 1: entire K=2048 loop from LDS, barrier-free; split-K 4 ways across
//            waves; w hi/lo fragments stream from L2 (wFs) — only VMEM in loop.
//   phase 2: combine split-K partials, sigmoid, tree -> P tile (LDS overlay).
//   phase 3: out rows = P_tile @ RT from RTs fragment stream; linear-ish
//            stores. P never touches HBM. 2 blocks/CU alternate phases.

typedef short bf16x8 __attribute__((ext_vector_type(8)));
typedef float f32x4  __attribute__((ext_vector_type(4)));

#define BS    32768
#define DIMX  2048
#define NODES 63
#define NL    64
#define DIMY  2048

__device__ __forceinline__ unsigned short f2bf(float f) {
    union { float f; unsigned int u; } v; v.f = f;
    unsigned int r = v.u + 0x7FFFu + ((v.u >> 16) & 1u);   // RNE
    return (unsigned short)(r >> 16);
}
__device__ __forceinline__ float bf2f(unsigned short h) {
    union { float f; unsigned int u; } v; v.u = ((unsigned int)h) << 16;
    return v.f;
}

// ---------------- kernel 0: prep --------------------------------------------
// wFs: frag id = (k>>5)*8 + g16*2 + hl ; element (lane l, e 0..7) =
//   wT[node = g16*16 + (l&15)][kcol = (k&~31) + (l>>4)*8 + e], hi or lo.
// RTs: frag id = nf*2 + kh ; element (l, e) = responses[kh*32+(l>>4)*8+e]
//   [nf*16 + (l&15)].
__global__ __launch_bounds__(256) void prep(const float* __restrict__ w,
                                            const float* __restrict__ R,
                                            unsigned short* __restrict__ wFs,
                                            unsigned short* __restrict__ RTs) {
    int f = blockIdx.x * 256 + threadIdx.x;     // 0..393215
    if (f < 262144) {                           // wFs
        int e   = f & 7;
        int l   = (f >> 3) & 63;
        int hl  = (f >> 9) & 1;
        int g16 = (f >> 10) & 3;
        int kk  = (f >> 12) & 1;
        int k   = f >> 13;                      // 0..31
        int n    = g16 * 16 + (l & 15);
        int kcol = k * 64 + kk * 32 + (l >> 4) * 8 + e;
        float v = (n < NODES) ? w[(size_t)kcol * NODES + n] : 0.0f;
        unsigned short h = f2bf(v);
        wFs[f] = hl ? f2bf(v - bf2f(h)) : h;
    } else {                                    // RTs
        int f2 = f - 262144;
        int e  = f2 & 7;
        int l  = (f2 >> 3) & 63;
        int kh = (f2 >> 9) & 1;
        int nf = f2 >> 10;                      // 0..127
        int k  = kh * 32 + (l >> 4) * 8 + e;    // leaf 0..63
        int n  = nf * 16 + (l & 15);            // dimy col
        RTs[f2] = f2bf(R[(size_t)k * DIMY + n]);
    }
}

// ---------------- kernel 1: fused gates + tree + out -------------------------
#define FBM 16      // rows per block

__global__ __launch_bounds__(256, 2) void fused_kernel(const float* __restrict__ x,
                                                       const unsigned short* __restrict__ wFs,
                                                       const float* __restrict__ bias,
                                                       const unsigned short* __restrict__ RTs,
                                                       float* __restrict__ out) {
    __shared__ __align__(16) unsigned char smem[65536];
    unsigned short* panel = (unsigned short*)smem;          // [16][2048] bf16, swizzled
    float* glp = (float*)smem;                              // [4][16][65] f32 (16.6 KB)
    float* gl  = (float*)(smem + 17408);                    // [16][65]    f32 (4.2 KB)
    unsigned short* pt = (unsigned short*)(smem + 22016);   // [16][72]    bf16 (2.3 KB)

    const int t    = threadIdx.x;
    const int lane = t & 63;
    const int wv   = t >> 6;        // 4 waves, split-K
    const int lr   = lane & 15;
    const int lg   = lane >> 4;
    const int m0   = blockIdx.x * FBM;

    // ---- phase 0: linear slab load -> swizzled bf16 panel ----
    // slab = 16 rows x 8 KB = 128 KB contiguous; thread t round i reads
    // float4 at f32-offset i*1024 + t*4 (perfectly linear across the block).
    {
        const float* xsl = x + (size_t)m0 * DIMX;
        #pragma unroll 8
        for (int i = 0; i < 32; ++i) {
            int o  = i * 1024 + t * 4;
            float4 v = *(const float4*)(xsl + o);
            int r  = o >> 11;
            int k2 = (o & 2047) * 2;            // byte col in row
            union { __hip_bfloat162 h[2]; unsigned long long u; } u2;
            u2.h[0] = __float22bfloat162_rn(make_float2(v.x, v.y));
            u2.h[1] = __float22bfloat162_rn(make_float2(v.z, v.w));
            *(unsigned long long*)((char*)panel + r * 4096 + (k2 ^ ((r & 7) << 4))) = u2.u;
        }
    }
    __syncthreads();                  // panel visible

    // ---- phase 1: K-loop from LDS, barrier-free; wave wv owns k half-K ----
    f32x4 acc[4];
    #pragma unroll
    for (int g = 0; g < 4; ++g) acc[g] = (f32x4){0.f, 0.f, 0.f, 0.f};

    {
        const unsigned short* wb = wFs + (size_t)lane * 8;
        const char* prow = (const char*)panel + lr * 4096;
        #pragma unroll 4
        for (int ks = 0; ks < 16; ++ks) {
            const int k = wv * 512 + ks * 32;   // bf16 k-index
            const int colb = (k + lg * 8) * 2;
            bf16x8 a = *(const bf16x8*)(prow + (colb ^ ((lr & 7) << 4)));
            const size_t fb = (size_t)(k >> 5) * 8 * 512;   // frag base (elems)
            #pragma unroll
            for (int g = 0; g < 4; ++g) {
                const unsigned short* p = wb + fb + (size_t)g * 1024;
                bf16x8 bh = *(const bf16x8*)p;
                bf16x8 bo = *(const bf16x8*)(p + 512);
                acc[g] = __builtin_amdgcn_mfma_f32_16x16x32_bf16(a, bh, acc[g], 0, 0, 0);
                acc[g] = __builtin_amdgcn_mfma_f32_16x16x32_bf16(a, bo, acc[g], 0, 0, 0);
            }
        }
    }
    __syncthreads();                  // panel reads done; reuse smem

    // ---- phase 2a: write split-K partials.  D-frag: row=lg*4+i, col=g*16+lr
    #pragma unroll
    for (int g = 0; g < 4; ++g)
        #pragma unroll
        for (int i = 0; i < 4; ++i)
            glp[wv * 1040 + (lg * 4 + i) * 65 + g * 16 + lr] = acc[g][i];
    __syncthreads();

    // ---- phase 2b: combine + bias + sigmoid -> gl (4 values/thread) ----
    #pragma unroll
    for (int ii = 0; ii < 4; ++ii) {
        int j = t * 4 + ii;
        int c = j & 63, r = j >> 6;
        float s = glp[r * 65 + c] + glp[1040 + r * 65 + c]
                + glp[2080 + r * 65 + c] + glp[3120 + r * 65 + c]
                + ((c < NODES) ? bias[c] : 0.0f);
        gl[r * 65 + c] = 1.0f / (1.0f + __expf(-s));
    }
    __syncthreads();

    // ---- phase 2c: tree -> P tile (16 thr/row, 4 leaves each) ----
    {
        const int rr  = t >> 4;       // 0..15
        const int sub = t & 15;
        const int b5 = sub & 1, b4 = (sub >> 1) & 1, qq = sub >> 2;
        const float* g = gl + rr * 65;
        float a2[2], a4[4], a8[8];
        float g0 = g[0];
        a2[0] = g0; a2[1] = 1.f - g0;
        #pragma unroll
        for (int m = 0; m < 4; ++m) {
            float gg = g[1 + (m & 1)];
            a4[m] = a2[m & 1] * ((m & 2) ? (1.f - gg) : gg);
        }
        #pragma unroll
        for (int m = 0; m < 8; ++m) {
            float gg = g[3 + (m & 3)];
            a8[m] = a4[m & 3] * ((m & 4) ? (1.f - gg) : gg);
        }
        unsigned short o[4];
        #pragma unroll
        for (int j = 0; j < 4; ++j) {
            int m = qq * 4 + j;                   // 0..15
            float g4 = g[7 + (m & 7)];
            float p  = a8[m & 7] * ((m & 8) ? (1.f - g4) : g4);
            float g5 = g[15 + m];
            p *= b4 ? (1.f - g5) : g5;
            float g6 = g[31 + m + 16 * b4];
            p *= b5 ? (1.f - g6) : g6;
            o[j] = f2bf(p);
        }
        uint2 qv;
        qv.x = (unsigned)o[0] | ((unsigned)o[1] << 16);
        qv.y = (unsigned)o[2] | ((unsigned)o[3] << 16);
        *(uint2*)&pt[rr * 72 + b5 * 32 + b4 * 16 + qq * 4] = qv;
    }
    __syncthreads();                  // P tile visible

    // ---- phase 3: out = P_tile @ RT; wave wv covers cols wv*512..+512 ----
    bf16x8 pa0 = *(const bf16x8*)&pt[lr * 72 + lg * 8];
    bf16x8 pa1 = *(const bf16x8*)&pt[lr * 72 + 32 + lg * 8];
    const unsigned short* rb = RTs + (size_t)lane * 8;
    float* op = out + (size_t)(m0 + lg * 4) * DIMY + lr;

    #pragma unroll 4
    for (int s = 0; s < 32; ++s) {
        const int nf = wv * 32 + s;
        bf16x8 c0 = *(const bf16x8*)(rb + (size_t)(nf * 2) * 512);
        bf16x8 c1 = *(const bf16x8*)(rb + (size_t)(nf * 2 + 1) * 512);
        f32x4 oa = (f32x4){0.f, 0.f, 0.f, 0.f};
        oa = __builtin_amdgcn_mfma_f32_16x16x32_bf16(pa0, c0, oa, 0, 0, 0);
        oa = __builtin_amdgcn_mfma_f32_16x16x32_bf16(pa1, c1, oa, 0, 0, 0);
        #pragma unroll
        for (int i = 0; i < 4; ++i)
            op[(size_t)i * DIMY + nf * 16] = oa[i];
    }
}

extern "C" void kernel_launch(void* const* d_in, const int* in_sizes, int n_in,
                              void* d_out, int out_size, void* d_ws, size_t ws_size,
                              hipStream_t stream) {
    const float* x = (const float*)d_in[0];
    const float* w = (const float*)d_in[1];
    const float* b = (const float*)d_in[2];
    const float* R = (const float*)d_in[3];
    float* out = (float*)d_out;

    char* ws = (char*)d_ws;
    unsigned short* wFs = (unsigned short*)ws;                  // 512 KB
    unsigned short* RTs = (unsigned short*)(ws + 524288);       // 256 KB

    prep<<<dim3(1536), 256, 0, stream>>>(w, R, wFs, RTs);
    fused_kernel<<<dim3(BS / FBM), 256, 0, stream>>>(x, wFs, b, RTs, out);
}